// Round 3
// baseline (8916.698 us; speedup 1.0000x reference)
//
#include <hip/hip_runtime.h>

#define HIDDEN 15
#define XDIM 8192
#define XOUT 8191
#define NL 5

#define REP15(F) F(0) F(1) F(2) F(3) F(4) F(5) F(6) F(7) F(8) F(9) F(10) F(11) F(12) F(13) F(14)

// 15-weight dot + bias, weights in 4 float4s (bias = q3.w), activations = named scalars P_0..P_14
#define DOTL(q0, q1, q2, q3, P)                                  \
    fmaf((q0).x, P##_0,                                          \
    fmaf((q0).y, P##_1,                                          \
    fmaf((q0).z, P##_2,                                          \
    fmaf((q0).w, P##_3,                                          \
    fmaf((q1).x, P##_4,                                          \
    fmaf((q1).y, P##_5,                                          \
    fmaf((q1).z, P##_6,                                          \
    fmaf((q1).w, P##_7,                                          \
    fmaf((q2).x, P##_8,                                          \
    fmaf((q2).y, P##_9,                                          \
    fmaf((q2).z, P##_10,                                         \
    fmaf((q2).w, P##_11,                                         \
    fmaf((q3).x, P##_12,                                         \
    fmaf((q3).y, P##_13,                                         \
    fmaf((q3).z, P##_14, (q3).w)))))))))))))))

__global__ __launch_bounds__(256, 4) void cnn_stencil_kernel(
    const float* __restrict__ rho,
    const float* __restrict__ w0,
    const float* __restrict__ b0,
    const float* __restrict__ Wh,
    const float* __restrict__ bh,
    const float* __restrict__ Wl,
    const float* __restrict__ bl,
    float* __restrict__ out) {
    __shared__ float sFC[HIDDEN][4];        // {w0[2c], w0[2c+1], b0[c], 0}
    __shared__ float sWh[NL][HIDDEN][16];   // [l][o][0..14]=Wh row, [15]=bh
    __shared__ float sWl[16];               // [0..14]=Wl, [15]=bl

    const int tid = threadIdx.x;

    // ---- stage weights into LDS (packed rows, bias in slot 15) ----
    for (int i = tid; i < NL * HIDDEN * 16; i += 256) {
        const int w = i >> 4;   // l*15 + o
        const int k = i & 15;
        (&sWh[0][0][0])[i] = (k < 15) ? Wh[w * 15 + k] : bh[w];
    }
    if (tid < HIDDEN * 4) {
        const int c = tid >> 2;
        const int k = tid & 3;
        sFC[c][k] = (k == 0) ? w0[2 * c] : (k == 1) ? w0[2 * c + 1] : (k == 2) ? b0[c] : 0.0f;
    }
    if (tid < 16) sWl[tid] = (tid < 15) ? Wl[tid] : bl[0];
    __syncthreads();

    const int b = blockIdx.x >> 4;             // 16 blocks per row
    const int chunk = blockIdx.x & 15;
    const int x0 = chunk * 512 + tid;          // [0, 7935]
    const int x1 = x0 + 256;                   // [256, 8191]
    const float* rrow = rho + (size_t)b * XDIM;
    float* orow = out + (size_t)b * XOUT;

    const float r00 = rrow[x0];
    const float r01 = rrow[x0 + 1];            // <= 7936, in bounds
    const float r10 = rrow[x1];
    const int x1n = (x1 + 1 <= XDIM - 1) ? (x1 + 1) : (XDIM - 1);
    const float r11 = rrow[x1n];

    // named scalar activations (never indexable -> guaranteed VGPRs)
#define DECLV(o) float a0_##o, a1_##o, t0_##o, t1_##o;
    REP15(DECLV)
#undef DECLV

    // ---- first conv (k=2) + relu ----
#define FCONV(c)                                                         \
    {                                                                    \
        const float4 q = *(const float4*)&sFC[c][0];                     \
        a0_##c = fmaxf(fmaf(q.x, r00, fmaf(q.y, r01, q.z)), 0.0f);       \
        a1_##c = fmaxf(fmaf(q.x, r10, fmaf(q.y, r11, q.z)), 0.0f);       \
    }
    REP15(FCONV)
#undef FCONV

    __builtin_amdgcn_sched_barrier(0);

    // ---- hidden 15x15 layers: weights read once, used for both positions ----
#define LAYER_O(l, o, SA, SB, DA, DB)                                    \
    {                                                                    \
        const float4 q0 = *(const float4*)&sWh[l][o][0];                 \
        const float4 q1 = *(const float4*)&sWh[l][o][4];                 \
        const float4 q2 = *(const float4*)&sWh[l][o][8];                 \
        const float4 q3 = *(const float4*)&sWh[l][o][12];                \
        DA##_##o = fmaxf(DOTL(q0, q1, q2, q3, SA), 0.0f);                \
        DB##_##o = fmaxf(DOTL(q0, q1, q2, q3, SB), 0.0f);                \
    }
#define LAYER(l, SA, SB, DA, DB)                                         \
    LAYER_O(l, 0, SA, SB, DA, DB)  LAYER_O(l, 1, SA, SB, DA, DB)         \
    LAYER_O(l, 2, SA, SB, DA, DB)  LAYER_O(l, 3, SA, SB, DA, DB)         \
    LAYER_O(l, 4, SA, SB, DA, DB)  LAYER_O(l, 5, SA, SB, DA, DB)         \
    LAYER_O(l, 6, SA, SB, DA, DB)  LAYER_O(l, 7, SA, SB, DA, DB)         \
    LAYER_O(l, 8, SA, SB, DA, DB)  LAYER_O(l, 9, SA, SB, DA, DB)         \
    LAYER_O(l, 10, SA, SB, DA, DB) LAYER_O(l, 11, SA, SB, DA, DB)        \
    LAYER_O(l, 12, SA, SB, DA, DB) LAYER_O(l, 13, SA, SB, DA, DB)        \
    LAYER_O(l, 14, SA, SB, DA, DB)

    LAYER(0, a0, a1, t0, t1)
    __builtin_amdgcn_sched_barrier(0);
    LAYER(1, t0, t1, a0, a1)
    __builtin_amdgcn_sched_barrier(0);
    LAYER(2, a0, a1, t0, t1)
    __builtin_amdgcn_sched_barrier(0);
    LAYER(3, t0, t1, a0, a1)
    __builtin_amdgcn_sched_barrier(0);
    LAYER(4, a0, a1, t0, t1)   // result in t0_*/t1_*
    __builtin_amdgcn_sched_barrier(0);
#undef LAYER
#undef LAYER_O

    // ---- final dot (bias = f3.w) + clip ----
    const float4 f0 = *(const float4*)&sWl[0];
    const float4 f1 = *(const float4*)&sWl[4];
    const float4 f2 = *(const float4*)&sWl[8];
    const float4 f3 = *(const float4*)&sWl[12];
    float y0 = DOTL(f0, f1, f2, f3, t0);
    float y1 = DOTL(f0, f1, f2, f3, t1);
    y0 = fminf(fmaxf(y0, 0.0f), 1.0f);
    y1 = fminf(fmaxf(y1, 0.0f), 1.0f);

    orow[x0] = y0;                  // x0 <= 7935 < 8191, always valid
    if (x1 < XOUT) orow[x1] = y1;   // mask single x==8191 slot
}

extern "C" void kernel_launch(void* const* d_in, const int* in_sizes, int n_in,
                              void* d_out, int out_size, void* d_ws, size_t ws_size,
                              hipStream_t stream) {
    const float* rho = (const float*)d_in[0];
    const float* w0  = (const float*)d_in[1];
    const float* b0  = (const float*)d_in[2];
    const float* Wh  = (const float*)d_in[3];
    const float* bh  = (const float*)d_in[4];
    const float* Wl  = (const float*)d_in[5];
    const float* bl  = (const float*)d_in[6];
    float* out = (float*)d_out;

    const int nrows = 1024;
    dim3 grid(nrows * 16);   // 16 blocks x 256 threads x 2 positions = 8192 slots/row
    dim3 block(256);
    cnn_stencil_kernel<<<grid, block, 0, stream>>>(rho, w0, b0, Wh, bh, Wl, bl, out);
}

// Round 4
// 590.285 us; speedup vs baseline: 15.1057x; 15.1057x over previous
//
#include <hip/hip_runtime.h>

#define XDIM 8192
#define XOUT 8191

#define REP15(F) F(0) F(1) F(2) F(3) F(4) F(5) F(6) F(7) F(8) F(9) F(10) F(11) F(12) F(13) F(14)

// 15-term dot + bias for hidden layer l, output row o, over named scalars P_0..P_14.
// Weight refs are wave-uniform with compile-time offsets -> s_load -> SGPR operand of v_fmac.
#define DOTH(l, o, P)                                            \
    fmaf(Wh[(l)*225+(o)*15+0],  P##_0,                           \
    fmaf(Wh[(l)*225+(o)*15+1],  P##_1,                           \
    fmaf(Wh[(l)*225+(o)*15+2],  P##_2,                           \
    fmaf(Wh[(l)*225+(o)*15+3],  P##_3,                           \
    fmaf(Wh[(l)*225+(o)*15+4],  P##_4,                           \
    fmaf(Wh[(l)*225+(o)*15+5],  P##_5,                           \
    fmaf(Wh[(l)*225+(o)*15+6],  P##_6,                           \
    fmaf(Wh[(l)*225+(o)*15+7],  P##_7,                           \
    fmaf(Wh[(l)*225+(o)*15+8],  P##_8,                           \
    fmaf(Wh[(l)*225+(o)*15+9],  P##_9,                           \
    fmaf(Wh[(l)*225+(o)*15+10], P##_10,                          \
    fmaf(Wh[(l)*225+(o)*15+11], P##_11,                          \
    fmaf(Wh[(l)*225+(o)*15+12], P##_12,                          \
    fmaf(Wh[(l)*225+(o)*15+13], P##_13,                          \
    fmaf(Wh[(l)*225+(o)*15+14], P##_14, bh[(l)*15+(o)])))))))))))))))

// final 15-term dot + bias
#define DOTF(P)                                                  \
    fmaf(Wl[0],  P##_0,                                          \
    fmaf(Wl[1],  P##_1,                                          \
    fmaf(Wl[2],  P##_2,                                          \
    fmaf(Wl[3],  P##_3,                                          \
    fmaf(Wl[4],  P##_4,                                          \
    fmaf(Wl[5],  P##_5,                                          \
    fmaf(Wl[6],  P##_6,                                          \
    fmaf(Wl[7],  P##_7,                                          \
    fmaf(Wl[8],  P##_8,                                          \
    fmaf(Wl[9],  P##_9,                                          \
    fmaf(Wl[10], P##_10,                                         \
    fmaf(Wl[11], P##_11,                                         \
    fmaf(Wl[12], P##_12,                                         \
    fmaf(Wl[13], P##_13,                                         \
    fmaf(Wl[14], P##_14, bl[0])))))))))))))))

// one output row: both positions reuse the same (SGPR) weight row
#define ROW(l, o, S, D)                                          \
    D##0_##o = fmaxf(DOTH(l, o, S##0), 0.0f);                    \
    D##1_##o = fmaxf(DOTH(l, o, S##1), 0.0f);

// 15x15 layer in 3 groups of 5 rows; sched_barrier(0) after each group keeps
// <= ~80 weight SGPRs live (prevents the allocator from hoisting s_loads and
// spilling SGPRs via v_writelane/v_readlane as in round 2).
#define LAYER(l, S, D)                                           \
    ROW(l, 0, S, D) ROW(l, 1, S, D) ROW(l, 2, S, D)              \
    ROW(l, 3, S, D) ROW(l, 4, S, D)                              \
    __builtin_amdgcn_sched_barrier(0);                           \
    ROW(l, 5, S, D) ROW(l, 6, S, D) ROW(l, 7, S, D)              \
    ROW(l, 8, S, D) ROW(l, 9, S, D)                              \
    __builtin_amdgcn_sched_barrier(0);                           \
    ROW(l, 10, S, D) ROW(l, 11, S, D) ROW(l, 12, S, D)           \
    ROW(l, 13, S, D) ROW(l, 14, S, D)                            \
    __builtin_amdgcn_sched_barrier(0);

__global__ __attribute__((amdgpu_flat_work_group_size(256, 256), amdgpu_waves_per_eu(4, 4)))
void cnn_stencil_kernel(
    const float* __restrict__ rho,
    const float* __restrict__ w0,
    const float* __restrict__ b0,
    const float* __restrict__ Wh,
    const float* __restrict__ bh,
    const float* __restrict__ Wl,
    const float* __restrict__ bl,
    float* __restrict__ out) {
    const int tid = threadIdx.x;
    const int b = blockIdx.x >> 4;             // 16 blocks per row
    const int chunk = blockIdx.x & 15;
    const int x0 = chunk * 512 + tid;          // [0, 7935]
    const int x1 = x0 + 256;                   // [256, 8191]
    const float* rrow = rho + (size_t)b * XDIM;
    float* orow = out + (size_t)b * XOUT;

    const float r00 = rrow[x0];
    const float r01 = rrow[x0 + 1];            // <= 7936, in bounds
    const float r10 = rrow[x1];
    const int x1n = (x1 + 1 <= XDIM - 1) ? (x1 + 1) : (XDIM - 1);
    const float r11 = rrow[x1n];

    // named scalar activations: never indexable -> guaranteed VGPR allocation
#define DECLV(o) float a0_##o, a1_##o, t0_##o, t1_##o;
    REP15(DECLV)
#undef DECLV

    // ---- first conv (k=2) + relu : 45 uniform scalars in this region ----
#define FC(c)                                                                    \
    a0_##c = fmaxf(fmaf(w0[2*(c)], r00, fmaf(w0[2*(c)+1], r01, b0[(c)])), 0.0f); \
    a1_##c = fmaxf(fmaf(w0[2*(c)], r10, fmaf(w0[2*(c)+1], r11, b0[(c)])), 0.0f);
    REP15(FC)
#undef FC
    __builtin_amdgcn_sched_barrier(0);

    // ---- 5 hidden 15x15 layers, ping-pong a <-> t ----
    LAYER(0, a, t)
    LAYER(1, t, a)
    LAYER(2, a, t)
    LAYER(3, t, a)
    LAYER(4, a, t)   // result in t0_* / t1_*

    // ---- final dot + clip ----
    float y0 = DOTF(t0);
    float y1 = DOTF(t1);
    y0 = fminf(fmaxf(y0, 0.0f), 1.0f);
    y1 = fminf(fmaxf(y1, 0.0f), 1.0f);

    orow[x0] = y0;                  // x0 <= 7935 < 8191, always valid
    if (x1 < XOUT) orow[x1] = y1;   // mask the single x==8191 slot
}

extern "C" void kernel_launch(void* const* d_in, const int* in_sizes, int n_in,
                              void* d_out, int out_size, void* d_ws, size_t ws_size,
                              hipStream_t stream) {
    const float* rho = (const float*)d_in[0];
    const float* w0  = (const float*)d_in[1];
    const float* b0  = (const float*)d_in[2];
    const float* Wh  = (const float*)d_in[3];
    const float* bh  = (const float*)d_in[4];
    const float* Wl  = (const float*)d_in[5];
    const float* bl  = (const float*)d_in[6];
    float* out = (float*)d_out;

    const int nrows = 1024;
    dim3 grid(nrows * 16);   // 16 blocks x 256 threads x 2 positions = 8192 slots/row
    dim3 block(256);
    cnn_stencil_kernel<<<grid, block, 0, stream>>>(rho, w0, b0, Wh, bh, Wl, bl, out);
}